// Round 21
// baseline (109.146 us; speedup 1.0000x reference)
//
#include <hip/hip_runtime.h>

#define VOCAB 16384
#define N_Q   16384   // B*h*w = 16*32*32
#define C     32
#define HW    1024    // h*w
#define VCH   16
#define CODES_PER_CH 1024
#define TILES_PER_CH 64
#define CHUNKB 147456     // per-chunk blob: [64KB hi | 64KB lo | 16KB eq]

typedef _Float16 half8 __attribute__((ext_vector_type(8)));
typedef float f32x4  __attribute__((ext_vector_type(4)));

// ---- fused prep: E -> per-chunk 144KB blobs (f16 hi/lo frags + enq quads),
//      + conv wpack + keys/counts/done init ----
// frag layout (HW-verified r6-r17): within tile, lane=(ko<<4)|(j&15), elem 0..7
__global__ __launch_bounds__(256) void k_prepE(const float* __restrict__ emb,
                                               char* __restrict__ Eblob,
                                               const float* __restrict__ convw,
                                               float* __restrict__ wp,
                                               unsigned long long* __restrict__ keys,
                                               int* __restrict__ counts,
                                               int* __restrict__ done) {
    int bx = blockIdx.x;
    if (bx >= 64) {
        if (bx == 64) {          // conv-weight repack to [tap][cin][cout]
            for (int k = threadIdx.x; k < C * C * 9; k += 256) {
                int cout = k / (C * 9);
                int r = k % (C * 9);
                int cin = r / 9;
                int tap = r % 9;
                wp[(tap * C + cin) * C + cout] = convw[k];
            }
        } else if (bx == 65) {
            for (int k = threadIdx.x; k < VOCAB; k += 256) keys[k] = ~0ULL;
        } else {
            for (int k = threadIdx.x; k < VOCAB; k += 256) counts[k] = 0;
            if (threadIdx.x == 0) *done = 0;
        }
        return;
    }
    int j = bx * 256 + threadIdx.x;   // code row
    const float4* e4 = reinterpret_cast<const float4*>(emb + j * C);
    float s = 0.f;
    float v[C];
#pragma unroll
    for (int k = 0; k < 8; ++k) {
        float4 t = e4[k];
        v[4 * k] = t.x; v[4 * k + 1] = t.y; v[4 * k + 2] = t.z; v[4 * k + 3] = t.w;
        s += t.x * t.x + t.y * t.y + t.z * t.z + t.w * t.w;
    }
    float en2 = 0.5f * s;
    int chunkid = j >> 10;            // 1024 codes per chunk
    int t = (j >> 4) & 63;            // tile within chunk
    char* gb = Eblob + (size_t)chunkid * CHUNKB;
    *reinterpret_cast<float4*>(gb + 131072 + t * 256 + (j & 15) * 16)
        = make_float4(en2, en2, en2, en2);
#pragma unroll
    for (int ko = 0; ko < 4; ++ko) {
        half8 vh, vl;
#pragma unroll
        for (int e = 0; e < 8; ++e) {
            float x = v[ko * 8 + e];
            _Float16 h = (_Float16)x;
            vh[e] = h;
            vl[e] = (_Float16)(x - (float)h);
        }
        int lane = (ko << 4) | (j & 15);
        *reinterpret_cast<half8*>(gb + t * 1024 + lane * 16) = vh;
        *reinterpret_cast<half8*>(gb + 65536 + t * 1024 + lane * 16) = vl;
    }
}

// ---- MFMA argmin: NO LDS, NO barriers — stream B-fragments straight from L2 ----
// d' = ||e||^2/2 - q.e ; f16 3-way split; block = 4 waves x 64 queries; grid (64,16)
__global__ __launch_bounds__(256, 4) void k_argmin(
    const float* __restrict__ f,
    const char* __restrict__ Eblob,
    unsigned long long* __restrict__ keys) {
    int tid = threadIdx.x;
    int lane = tid & 63;
    int w = tid >> 6;
    int wid = blockIdx.x * 4 + w;        // 0..255, 64 queries each
    int chunk = blockIdx.y;

    // Q prologue: 64 queries from f (NCHW), negate, f16 hi/lo split
    half8 a_hi[4], a_lo[4];
    int c0 = (lane >> 4) * 8;
#pragma unroll
    for (int qq = 0; qq < 4; ++qq) {
        int n = (wid * 4 + qq) * 16 + (lane & 15);
        int b = n >> 10, rem = n & 1023;
        const float* fp = f + (b * C + c0) * HW + rem;
#pragma unroll
        for (int e = 0; e < 8; ++e) {
            float x = -fp[e * HW];            // negated
            _Float16 h = (_Float16)x;
            a_hi[qq][e] = h;
            a_lo[qq][e] = (_Float16)(x - (float)h);
        }
    }

    float best[4][4];
#pragma unroll
    for (int qq = 0; qq < 4; ++qq)
#pragma unroll
        for (int r = 0; r < 4; ++r) best[qq][r] = __uint_as_float(0x7F800000u);  // +inf

    unsigned mpack = 0xFFFFFFC0u;
    // keep mask in a register so (x & m) | t fuses to v_and_or_b32 (t stays SGPR)
    asm("" : "+v"(mpack));

    const char* gb  = Eblob + (size_t)chunk * CHUNKB;
    const char* gbl = gb + lane * 16;                  // hi/lo per-lane base (L2-hot)
    const char* gel = gb + 131072 + (lane & 15) * 16;  // eq base (L2-hot)

    for (int tt = 0; tt < TILES_PER_CH; ++tt) {
        half8 bh = *(const half8*)(gbl + tt * 1024);
        half8 bl = *(const half8*)(gbl + 65536 + tt * 1024);
        f32x4 eq = *(const f32x4*)(gel + tt * 256);
        unsigned t = (unsigned)tt;
#pragma unroll
        for (int qq = 0; qq < 4; ++qq) {
            f32x4 acc = __builtin_amdgcn_mfma_f32_16x16x32_f16(a_hi[qq], bh, eq, 0, 0, 0);
            acc = __builtin_amdgcn_mfma_f32_16x16x32_f16(a_hi[qq], bl, acc, 0, 0, 0);
            acc = __builtin_amdgcn_mfma_f32_16x16x32_f16(a_lo[qq], bh, acc, 0, 0, 0);
#pragma unroll
            for (int r = 0; r < 4; ++r) {
                unsigned p = (__float_as_uint(acc[r]) & mpack) | t;   // v_and_or_b32
                best[qq][r] = fminf(best[qq][r], __uint_as_float(p)); // v_min_f32
            }
        }
    }

    // 16-lane column reduce per query row, then one atomicMin per query
#pragma unroll
    for (int qq = 0; qq < 4; ++qq)
#pragma unroll
        for (int r = 0; r < 4; ++r) {
            float d = best[qq][r];
            int t = (int)(__float_as_uint(d) & 63u);
            int code = chunk * CODES_PER_CH + (t << 4) + (lane & 15);
#pragma unroll
            for (int m = 1; m < 16; m <<= 1) {
                float od = __shfl_xor(d, m, 64);
                int oc = __shfl_xor(code, m, 64);
                if (od < d || (od == d && oc < code)) { d = od; code = oc; }
            }
            if ((lane & 15) == 0) {
                int row = ((lane >> 4) * 4) + r;
                int n = (wid * 4 + qq) * 16 + row;
                unsigned bits = __float_as_uint(d);
                unsigned s = ((int)bits >= 0) ? (bits | 0x80000000u) : ~bits;
                unsigned long long key = ((unsigned long long)s << 32) | (unsigned)code;
                atomicMin(&keys[n], key);
            }
        }
}

// ---- conv3x3 residual + fhat + loss + bincount + FUSED final scalars ----
__global__ __launch_bounds__(256) void k_conv(const unsigned long long* __restrict__ keys,
                                              const float* __restrict__ emb,
                                              const float* __restrict__ wp,
                                              const float* __restrict__ bias,
                                              const float* __restrict__ f,
                                              int* __restrict__ counts,
                                              float* __restrict__ out,
                                              float* __restrict__ lpart,
                                              int* __restrict__ done) {
    __shared__ float sZ[128 * 33];
    __shared__ float sW[9216];      // full [tap][cin][cout] weight block
    __shared__ float red[256];
    __shared__ int sfin;
    int blk = blockIdx.x;
    int b = blk >> 4;
    int r0 = (blk & 15) * 2;
    int tid = threadIdx.x;

    {   // stage weights: 2304 float4
        float4* dW = reinterpret_cast<float4*>(sW);
        const float4* sWp = reinterpret_cast<const float4*>(wp);
        for (int i = tid; i < 2304; i += 256) dW[i] = sWp[i];
    }
    {   // stage 4 rows (r0-1..r0+2)
        int px = tid >> 1, half = tid & 1;
        int row = px >> 5, col = px & 31;
        int gy = r0 - 1 + row;
        float* d = &sZ[px * 33 + half * 16];
        if (gy >= 0 && gy < 32) {
            int id = (int)(keys[b * HW + gy * 32 + col] & 0xFFFFFFFFULL);
            const float4* s = reinterpret_cast<const float4*>(emb + id * C + half * 16);
#pragma unroll
            for (int k = 0; k < 4; ++k) {
                float4 v = s[k];
                d[4 * k] = v.x; d[4 * k + 1] = v.y; d[4 * k + 2] = v.z; d[4 * k + 3] = v.w;
            }
        } else {
#pragma unroll
            for (int k = 0; k < 16; ++k) d[k] = 0.f;
        }
    }
    __syncthreads();

    int tx = tid & 31, ty = (tid >> 5) & 1, cg = tid >> 6;
    int co0 = cg * 8;
    int gy = r0 + ty;
    if (cg == 0) {
        int id = (int)(keys[b * HW + gy * 32 + tx] & 0xFFFFFFFFULL);
        atomicAdd(&counts[id], 1);
    }
    float acc[8];
#pragma unroll
    for (int u = 0; u < 8; ++u) acc[u] = bias[co0 + u];
    for (int dy = -1; dy <= 1; ++dy) {
        for (int dx = -1; dx <= 1; ++dx) {
            int gx = tx + dx;
            if (gx < 0 || gx >= 32) continue;
            const float* zp = &sZ[((ty + 1 + dy) * 32 + gx) * 33];
            int tap = (dy + 1) * 3 + (dx + 1);
            const float* wtap = &sW[tap * C * C + co0];
#pragma unroll
            for (int cin = 0; cin < C; ++cin) {
                float z = zp[cin];
                const f32x4* w4 = reinterpret_cast<const f32x4*>(wtap + cin * C);
                f32x4 wa = w4[0], wb = w4[1];
#pragma unroll
                for (int u = 0; u < 4; ++u) acc[u] = fmaf(z, wa[u], acc[u]);
#pragma unroll
                for (int u = 0; u < 4; ++u) acc[4 + u] = fmaf(z, wb[u], acc[4 + u]);
            }
        }
    }
    float lsum = 0.f;
#pragma unroll
    for (int u = 0; u < 8; ++u) {
        int cc = co0 + u;
        float zqv = sZ[((ty + 1) * 32 + tx) * 33 + cc];
        float fh = 0.5f * (zqv + acc[u]);   // h*(1-r) + (conv+b)*r, r=0.5
        int off = (b * C + cc) * HW + gy * 32 + tx;
        out[off] = fh;
        float diff = fh - f[off];
        lsum += diff * diff;
    }
    red[tid] = lsum;
    __syncthreads();
    for (int s = 128; s > 0; s >>= 1) {
        if (tid < s) red[tid] += red[tid + s];
        __syncthreads();
    }
    if (tid == 0) lpart[blk] = red[0];

    // ---- last-block fused finalization ----
    if (tid == 0) {
        __threadfence();                       // publish lpart + count atomics
        int v = atomicAdd(done, 1);
        sfin = (v == 255) ? 1 : 0;
    }
    __syncthreads();
    if (sfin) {
        __threadfence();                       // acquire all blocks' writes
        int* redi = (int*)sZ;                  // reuse LDS
        int used = 0;
        for (int i = tid; i < VOCAB; i += 256) used += (counts[i] != 0) ? 1 : 0;
        red[tid] = lpart[tid];
        redi[tid] = used;
        __syncthreads();
        for (int s = 128; s > 0; s >>= 1) {
            if (tid < s) { red[tid] += red[tid + s]; redi[tid] += redi[tid + s]; }
            __syncthreads();
        }
        if (tid == 0) {
            out[N_Q * C]     = 1.25f * red[0] / (float)(N_Q * C);      // (1+BETA)*MSE
            out[N_Q * C + 1] = 100.f * (float)redi[0] / (float)VOCAB;  // counts>=1
        }
    }
}

extern "C" void kernel_launch(void* const* d_in, const int* in_sizes, int n_in,
                              void* d_out, int out_size, void* d_ws, size_t ws_size,
                              hipStream_t stream) {
    const float* f     = (const float*)d_in[0];
    const float* emb   = (const float*)d_in[1];
    const float* convw = (const float*)d_in[2];
    const float* convb = (const float*)d_in[3];
    float* out = (float*)d_out;
    float* ws  = (float*)d_ws;

    // float-unit offsets (total ~2.6 MB)
    float*  wp     = ws;                              // 9216
    float*  lpart  = ws + 9216;                       // 256
    int*    done   = (int*)(ws + 9472);               // 16 (padded)
    int*    counts = (int*)(ws + 9488);               // 16384
    unsigned long long* keys = (unsigned long long*)(ws + 25872);  // 16384 u64 (8B-aligned)
    char*   Eblob  = (char*)(ws + 58640);             // 16 chunks x 144KB = 2.304 MB (16B-aligned)

    k_prepE<<<67, 256, 0, stream>>>(emb, Eblob, convw, wp, keys, counts, done);
    dim3 g2(64, VCH);
    k_argmin<<<g2, 256, 0, stream>>>(f, Eblob, keys);
    k_conv<<<256, 256, 0, stream>>>(keys, emb, wp, convb, f, counts, out, lpart, done);
}

// Round 22
// 97.909 us; speedup vs baseline: 1.1148x; 1.1148x over previous
//
#include <hip/hip_runtime.h>

#define VOCAB 16384
#define N_Q   16384   // B*h*w = 16*32*32
#define C     32
#define HW    1024    // h*w
#define VCH   16
#define CODES_PER_CH 1024
#define TILES_PER_CH 64
#define CHUNKB 147456     // per-chunk blob: [64KB hi | 64KB lo | 16KB eq]
#define WBUF   9216       // per-wave buffer: [4KB hi | 4KB lo | 1KB eq]

typedef _Float16 half8 __attribute__((ext_vector_type(8)));
typedef float f32x4  __attribute__((ext_vector_type(4)));

// ---- fused prep: E -> per-chunk 144KB blobs (f16 hi/lo frags + enq quads),
//      + conv wpack + keys/counts/done init ----
// frag layout (HW-verified r6-r21): within tile, lane=(ko<<4)|(j&15), elem 0..7
__global__ __launch_bounds__(256) void k_prepE(const float* __restrict__ emb,
                                               char* __restrict__ Eblob,
                                               const float* __restrict__ convw,
                                               float* __restrict__ wp,
                                               unsigned long long* __restrict__ keys,
                                               int* __restrict__ counts,
                                               int* __restrict__ done) {
    int bx = blockIdx.x;
    if (bx >= 64) {
        if (bx == 64) {          // conv-weight repack to [tap][cin][cout]
            for (int k = threadIdx.x; k < C * C * 9; k += 256) {
                int cout = k / (C * 9);
                int r = k % (C * 9);
                int cin = r / 9;
                int tap = r % 9;
                wp[(tap * C + cin) * C + cout] = convw[k];
            }
        } else if (bx == 65) {
            for (int k = threadIdx.x; k < VOCAB; k += 256) keys[k] = ~0ULL;
        } else {
            for (int k = threadIdx.x; k < VOCAB; k += 256) counts[k] = 0;
            if (threadIdx.x == 0) *done = 0;
        }
        return;
    }
    int j = bx * 256 + threadIdx.x;   // code row
    const float4* e4 = reinterpret_cast<const float4*>(emb + j * C);
    float s = 0.f;
    float v[C];
#pragma unroll
    for (int k = 0; k < 8; ++k) {
        float4 t = e4[k];
        v[4 * k] = t.x; v[4 * k + 1] = t.y; v[4 * k + 2] = t.z; v[4 * k + 3] = t.w;
        s += t.x * t.x + t.y * t.y + t.z * t.z + t.w * t.w;
    }
    float en2 = 0.5f * s;
    int chunkid = j >> 10;            // 1024 codes per chunk
    int t = (j >> 4) & 63;            // tile within chunk
    char* gb = Eblob + (size_t)chunkid * CHUNKB;
    *reinterpret_cast<float4*>(gb + 131072 + t * 256 + (j & 15) * 16)
        = make_float4(en2, en2, en2, en2);
#pragma unroll
    for (int ko = 0; ko < 4; ++ko) {
        half8 vh, vl;
#pragma unroll
        for (int e = 0; e < 8; ++e) {
            float x = v[ko * 8 + e];
            _Float16 h = (_Float16)x;
            vh[e] = h;
            vl[e] = (_Float16)(x - (float)h);
        }
        int lane = (ko << 4) | (j & 15);
        *reinterpret_cast<half8*>(gb + t * 1024 + lane * 16) = vh;
        *reinterpret_cast<half8*>(gb + 65536 + t * 1024 + lane * 16) = vl;
    }
}

// ---- stage one 9KB group (4 tiles) into THIS WAVE's private LDS buffer ----
// 9 x 1KB linear copies; all per-wave (global_load_lds + vmcnt are wave-scoped)
__device__ __forceinline__ void stage_grp(const char* gb, int g, char* db, int lane) {
#pragma unroll
    for (int c = 0; c < 4; ++c)       // hi: 4 tiles
        __builtin_amdgcn_global_load_lds(
            (const __attribute__((address_space(1))) void*)(gb + g * 4096 + c * 1024 + lane * 16),
            (__attribute__((address_space(3))) void*)(db + c * 1024 + lane * 16), 16, 0, 0);
#pragma unroll
    for (int c = 0; c < 4; ++c)       // lo: 4 tiles
        __builtin_amdgcn_global_load_lds(
            (const __attribute__((address_space(1))) void*)(gb + 65536 + g * 4096 + c * 1024 + lane * 16),
            (__attribute__((address_space(3))) void*)(db + 4096 + c * 1024 + lane * 16), 16, 0, 0);
    __builtin_amdgcn_global_load_lds(  // eq: 1KB
        (const __attribute__((address_space(1))) void*)(gb + 131072 + g * 1024 + lane * 16),
        (__attribute__((address_space(3))) void*)(db + 8192 + lane * 16), 16, 0, 0);
}

// ---- MFMA argmin: per-wave-private LDS double-buffer, ZERO barriers ----
// d' = ||e||^2/2 - q.e ; f16 3-way split; block = 4 waves x 64 queries; grid (64,16)
// 72KB LDS/block -> 2 blocks/CU (8 waves); counted vmcnt(9) keeps next group in flight
__global__ __launch_bounds__(256, 2) void k_argmin(
    const float* __restrict__ f,
    const char* __restrict__ Eblob,
    unsigned long long* __restrict__ keys) {
    __shared__ __align__(16) char lds[4 * 2 * WBUF];   // 4 waves x 2 private buffers
    int tid = threadIdx.x;
    int lane = tid & 63;
    int w = tid >> 6;
    int wid = blockIdx.x * 4 + w;        // 0..255, 64 queries each
    int chunk = blockIdx.y;
    char* buf0 = lds + w * (2 * WBUF);   // this wave's region

    // Q prologue: 64 queries from f (NCHW), negate, f16 hi/lo split
    half8 a_hi[4], a_lo[4];
    int c0 = (lane >> 4) * 8;
#pragma unroll
    for (int qq = 0; qq < 4; ++qq) {
        int n = (wid * 4 + qq) * 16 + (lane & 15);
        int b = n >> 10, rem = n & 1023;
        const float* fp = f + (b * C + c0) * HW + rem;
#pragma unroll
        for (int e = 0; e < 8; ++e) {
            float x = -fp[e * HW];            // negated
            _Float16 h = (_Float16)x;
            a_hi[qq][e] = h;
            a_lo[qq][e] = (_Float16)(x - (float)h);
        }
    }

    float best[4][4];
#pragma unroll
    for (int qq = 0; qq < 4; ++qq)
#pragma unroll
        for (int r = 0; r < 4; ++r) best[qq][r] = __uint_as_float(0x7F800000u);  // +inf

    unsigned mpack = 0xFFFFFFC0u;
    // keep mask in a register so (x & m) | t fuses to v_and_or_b32 (t stays SGPR)
    asm("" : "+v"(mpack));

    const char* gb = Eblob + (size_t)chunk * CHUNKB;

    stage_grp(gb, 0, buf0, lane);        // prologue: group 0 in flight

    for (int g = 0; g < 16; ++g) {       // 16 groups x 4 tiles
        if (g < 15) {
            stage_grp(gb, g + 1, buf0 + ((g + 1) & 1) * WBUF, lane);
            asm volatile("s_waitcnt vmcnt(9)" ::: "memory");  // group g resident; g+1 in flight
        } else {
            asm volatile("s_waitcnt vmcnt(0)" ::: "memory");
        }
        __builtin_amdgcn_sched_barrier(0);  // rule #18: pin LDS reads after the wait
        const char* bb = buf0 + (g & 1) * WBUF;
#pragma unroll
        for (int tt = 0; tt < 4; ++tt) {
            half8 bh = *(const half8*)(bb + tt * 1024 + lane * 16);
            half8 bl = *(const half8*)(bb + 4096 + tt * 1024 + lane * 16);
            f32x4 eq = *(const f32x4*)(bb + 8192 + tt * 256 + (lane & 15) * 16);
            unsigned t = (unsigned)(g * 4 + tt);
#pragma unroll
            for (int qq = 0; qq < 4; ++qq) {
                f32x4 acc = __builtin_amdgcn_mfma_f32_16x16x32_f16(a_hi[qq], bh, eq, 0, 0, 0);
                acc = __builtin_amdgcn_mfma_f32_16x16x32_f16(a_hi[qq], bl, acc, 0, 0, 0);
                acc = __builtin_amdgcn_mfma_f32_16x16x32_f16(a_lo[qq], bh, acc, 0, 0, 0);
#pragma unroll
                for (int r = 0; r < 4; ++r) {
                    unsigned p = (__float_as_uint(acc[r]) & mpack) | t;   // v_and_or_b32
                    best[qq][r] = fminf(best[qq][r], __uint_as_float(p)); // v_min_f32
                }
            }
        }
    }

    // 16-lane column reduce per query row, then one atomicMin per query
#pragma unroll
    for (int qq = 0; qq < 4; ++qq)
#pragma unroll
        for (int r = 0; r < 4; ++r) {
            float d = best[qq][r];
            int t = (int)(__float_as_uint(d) & 63u);
            int code = chunk * CODES_PER_CH + (t << 4) + (lane & 15);
#pragma unroll
            for (int m = 1; m < 16; m <<= 1) {
                float od = __shfl_xor(d, m, 64);
                int oc = __shfl_xor(code, m, 64);
                if (od < d || (od == d && oc < code)) { d = od; code = oc; }
            }
            if ((lane & 15) == 0) {
                int row = ((lane >> 4) * 4) + r;
                int n = (wid * 4 + qq) * 16 + row;
                unsigned bits = __float_as_uint(d);
                unsigned s = ((int)bits >= 0) ? (bits | 0x80000000u) : ~bits;
                unsigned long long key = ((unsigned long long)s << 32) | (unsigned)code;
                atomicMin(&keys[n], key);
            }
        }
}

// ---- conv3x3 residual + fhat + loss + bincount + FUSED final scalars ----
__global__ __launch_bounds__(256) void k_conv(const unsigned long long* __restrict__ keys,
                                              const float* __restrict__ emb,
                                              const float* __restrict__ wp,
                                              const float* __restrict__ bias,
                                              const float* __restrict__ f,
                                              int* __restrict__ counts,
                                              float* __restrict__ out,
                                              float* __restrict__ lpart,
                                              int* __restrict__ done) {
    __shared__ float sZ[128 * 33];
    __shared__ float sW[9216];      // full [tap][cin][cout] weight block
    __shared__ float red[256];
    __shared__ int sfin;
    int blk = blockIdx.x;
    int b = blk >> 4;
    int r0 = (blk & 15) * 2;
    int tid = threadIdx.x;

    {   // stage weights: 2304 float4
        float4* dW = reinterpret_cast<float4*>(sW);
        const float4* sWp = reinterpret_cast<const float4*>(wp);
        for (int i = tid; i < 2304; i += 256) dW[i] = sWp[i];
    }
    {   // stage 4 rows (r0-1..r0+2)
        int px = tid >> 1, half = tid & 1;
        int row = px >> 5, col = px & 31;
        int gy = r0 - 1 + row;
        float* d = &sZ[px * 33 + half * 16];
        if (gy >= 0 && gy < 32) {
            int id = (int)(keys[b * HW + gy * 32 + col] & 0xFFFFFFFFULL);
            const float4* s = reinterpret_cast<const float4*>(emb + id * C + half * 16);
#pragma unroll
            for (int k = 0; k < 4; ++k) {
                float4 v = s[k];
                d[4 * k] = v.x; d[4 * k + 1] = v.y; d[4 * k + 2] = v.z; d[4 * k + 3] = v.w;
            }
        } else {
#pragma unroll
            for (int k = 0; k < 16; ++k) d[k] = 0.f;
        }
    }
    __syncthreads();

    int tx = tid & 31, ty = (tid >> 5) & 1, cg = tid >> 6;
    int co0 = cg * 8;
    int gy = r0 + ty;
    if (cg == 0) {
        int id = (int)(keys[b * HW + gy * 32 + tx] & 0xFFFFFFFFULL);
        atomicAdd(&counts[id], 1);
    }
    float acc[8];
#pragma unroll
    for (int u = 0; u < 8; ++u) acc[u] = bias[co0 + u];
    for (int dy = -1; dy <= 1; ++dy) {
        for (int dx = -1; dx <= 1; ++dx) {
            int gx = tx + dx;
            if (gx < 0 || gx >= 32) continue;
            const float* zp = &sZ[((ty + 1 + dy) * 32 + gx) * 33];
            int tap = (dy + 1) * 3 + (dx + 1);
            const float* wtap = &sW[tap * C * C + co0];
#pragma unroll
            for (int cin = 0; cin < C; ++cin) {
                float z = zp[cin];
                const f32x4* w4 = reinterpret_cast<const f32x4*>(wtap + cin * C);
                f32x4 wa = w4[0], wb = w4[1];
#pragma unroll
                for (int u = 0; u < 4; ++u) acc[u] = fmaf(z, wa[u], acc[u]);
#pragma unroll
                for (int u = 0; u < 4; ++u) acc[4 + u] = fmaf(z, wb[u], acc[4 + u]);
            }
        }
    }
    float lsum = 0.f;
#pragma unroll
    for (int u = 0; u < 8; ++u) {
        int cc = co0 + u;
        float zqv = sZ[((ty + 1) * 32 + tx) * 33 + cc];
        float fh = 0.5f * (zqv + acc[u]);   // h*(1-r) + (conv+b)*r, r=0.5
        int off = (b * C + cc) * HW + gy * 32 + tx;
        out[off] = fh;
        float diff = fh - f[off];
        lsum += diff * diff;
    }
    red[tid] = lsum;
    __syncthreads();
    for (int s = 128; s > 0; s >>= 1) {
        if (tid < s) red[tid] += red[tid + s];
        __syncthreads();
    }
    if (tid == 0) lpart[blk] = red[0];

    // ---- last-block fused finalization ----
    if (tid == 0) {
        __threadfence();                       // publish lpart + count atomics
        int v = atomicAdd(done, 1);
        sfin = (v == 255) ? 1 : 0;
    }
    __syncthreads();
    if (sfin) {
        __threadfence();                       // acquire all blocks' writes
        int* redi = (int*)sZ;                  // reuse LDS
        int used = 0;
        for (int i = tid; i < VOCAB; i += 256) used += (counts[i] != 0) ? 1 : 0;
        red[tid] = lpart[tid];
        redi[tid] = used;
        __syncthreads();
        for (int s = 128; s > 0; s >>= 1) {
            if (tid < s) { red[tid] += red[tid + s]; redi[tid] += redi[tid + s]; }
            __syncthreads();
        }
        if (tid == 0) {
            out[N_Q * C]     = 1.25f * red[0] / (float)(N_Q * C);      // (1+BETA)*MSE
            out[N_Q * C + 1] = 100.f * (float)redi[0] / (float)VOCAB;  // counts>=1
        }
    }
}

extern "C" void kernel_launch(void* const* d_in, const int* in_sizes, int n_in,
                              void* d_out, int out_size, void* d_ws, size_t ws_size,
                              hipStream_t stream) {
    const float* f     = (const float*)d_in[0];
    const float* emb   = (const float*)d_in[1];
    const float* convw = (const float*)d_in[2];
    const float* convb = (const float*)d_in[3];
    float* out = (float*)d_out;
    float* ws  = (float*)d_ws;

    // float-unit offsets (total ~2.6 MB)
    float*  wp     = ws;                              // 9216
    float*  lpart  = ws + 9216;                       // 256
    int*    done   = (int*)(ws + 9472);               // 16 (padded)
    int*    counts = (int*)(ws + 9488);               // 16384
    unsigned long long* keys = (unsigned long long*)(ws + 25872);  // 16384 u64 (8B-aligned)
    char*   Eblob  = (char*)(ws + 58640);             // 16 chunks x 144KB = 2.304 MB (16B-aligned)

    k_prepE<<<67, 256, 0, stream>>>(emb, Eblob, convw, wp, keys, counts, done);
    dim3 g2(64, VCH);
    k_argmin<<<g2, 256, 0, stream>>>(f, Eblob, keys);
    k_conv<<<256, 256, 0, stream>>>(keys, emb, wp, convb, f, counts, out, lpart, done);
}

// Round 23
// 96.332 us; speedup vs baseline: 1.1330x; 1.0164x over previous
//
#include <hip/hip_runtime.h>

#define VOCAB 16384
#define N_Q   16384   // B*h*w = 16*32*32
#define C     32
#define HW    1024    // h*w
#define VCH   16
#define CODES_PER_CH 1024
#define NGRP2  32         // 2-tile groups per chunk
#define GB2    5120       // group blob: [2KB hi | 2KB lo | 1KB eq(512B used)]
#define CHUNKB (NGRP2 * GB2)   // 163840 B per chunk
#define WBUF   5120       // per-wave LDS buffer (one group)

typedef _Float16 half8 __attribute__((ext_vector_type(8)));
typedef float f32x4  __attribute__((ext_vector_type(4)));

// ---- fused prep: E -> per-chunk blobs of 2-tile 5KB groups + wpack + init ----
// frag layout (HW-verified r6-r22): within tile, lane=(ko<<4)|(j&15), elem 0..7
__global__ __launch_bounds__(256) void k_prepE(const float* __restrict__ emb,
                                               char* __restrict__ Eblob,
                                               const float* __restrict__ convw,
                                               float* __restrict__ wp,
                                               unsigned long long* __restrict__ keys,
                                               int* __restrict__ counts,
                                               int* __restrict__ done) {
    int bx = blockIdx.x;
    if (bx >= 64) {
        if (bx == 64) {          // conv-weight repack to [tap][cin][cout]
            for (int k = threadIdx.x; k < C * C * 9; k += 256) {
                int cout = k / (C * 9);
                int r = k % (C * 9);
                int cin = r / 9;
                int tap = r % 9;
                wp[(tap * C + cin) * C + cout] = convw[k];
            }
        } else if (bx == 65) {
            for (int k = threadIdx.x; k < VOCAB; k += 256) keys[k] = ~0ULL;
        } else {
            for (int k = threadIdx.x; k < VOCAB; k += 256) counts[k] = 0;
            if (threadIdx.x == 0) *done = 0;
        }
        return;
    }
    int j = bx * 256 + threadIdx.x;   // code row
    const float4* e4 = reinterpret_cast<const float4*>(emb + j * C);
    float s = 0.f;
    float v[C];
#pragma unroll
    for (int k = 0; k < 8; ++k) {
        float4 t = e4[k];
        v[4 * k] = t.x; v[4 * k + 1] = t.y; v[4 * k + 2] = t.z; v[4 * k + 3] = t.w;
        s += t.x * t.x + t.y * t.y + t.z * t.z + t.w * t.w;
    }
    float en2 = 0.5f * s;
    int chunkid = j >> 10;            // 1024 codes per chunk
    int t = (j >> 4) & 63;            // tile within chunk
    int G2 = t >> 1, sub = t & 1;     // 2-tile group, slot within group
    char* gb = Eblob + (size_t)chunkid * CHUNKB + (size_t)G2 * GB2;
    *reinterpret_cast<float4*>(gb + 4096 + sub * 256 + (j & 15) * 16)
        = make_float4(en2, en2, en2, en2);
#pragma unroll
    for (int ko = 0; ko < 4; ++ko) {
        half8 vh, vl;
#pragma unroll
        for (int e = 0; e < 8; ++e) {
            float x = v[ko * 8 + e];
            _Float16 h = (_Float16)x;
            vh[e] = h;
            vl[e] = (_Float16)(x - (float)h);
        }
        int lane = (ko << 4) | (j & 15);
        *reinterpret_cast<half8*>(gb + sub * 1024 + lane * 16) = vh;
        *reinterpret_cast<half8*>(gb + 2048 + sub * 1024 + lane * 16) = vl;
    }
}

// ---- stage one contiguous 5KB group into THIS WAVE's private LDS buffer ----
// 5 x 1KB linear copies; per-wave scoped (global_load_lds + vmcnt are wave ops)
__device__ __forceinline__ void stage_grp(const char* gb, int g, char* db, int lane) {
    const char* src = gb + (size_t)g * GB2;
#pragma unroll
    for (int c = 0; c < 5; ++c)
        __builtin_amdgcn_global_load_lds(
            (const __attribute__((address_space(1))) void*)(src + c * 1024 + lane * 16),
            (__attribute__((address_space(3))) void*)(db + c * 1024 + lane * 16), 16, 0, 0);
}

// ---- MFMA argmin: per-wave private LDS dbuf, ZERO barriers, 4 blocks/CU ----
// d' = ||e||^2/2 - q.e ; f16 3-way split; block = 4 waves x 64 queries; grid (64,16)
// 40KB LDS/block -> 4 blocks/CU (16 waves); counted vmcnt(5), never drained mid-loop
__global__ __launch_bounds__(256, 4) void k_argmin(
    const float* __restrict__ f,
    const char* __restrict__ Eblob,
    unsigned long long* __restrict__ keys) {
    __shared__ __align__(16) char lds[4 * 2 * WBUF];   // 4 waves x 2 private buffers
    int tid = threadIdx.x;
    int lane = tid & 63;
    int w = tid >> 6;
    int wid = blockIdx.x * 4 + w;        // 0..255, 64 queries each
    int chunk = blockIdx.y;
    char* buf0 = lds + w * (2 * WBUF);   // this wave's region

    // Q prologue: 64 queries from f (NCHW), negate, f16 hi/lo split
    half8 a_hi[4], a_lo[4];
    int c0 = (lane >> 4) * 8;
#pragma unroll
    for (int qq = 0; qq < 4; ++qq) {
        int n = (wid * 4 + qq) * 16 + (lane & 15);
        int b = n >> 10, rem = n & 1023;
        const float* fp = f + (b * C + c0) * HW + rem;
#pragma unroll
        for (int e = 0; e < 8; ++e) {
            float x = -fp[e * HW];            // negated
            _Float16 h = (_Float16)x;
            a_hi[qq][e] = h;
            a_lo[qq][e] = (_Float16)(x - (float)h);
        }
    }

    float best[4][4];
#pragma unroll
    for (int qq = 0; qq < 4; ++qq)
#pragma unroll
        for (int r = 0; r < 4; ++r) best[qq][r] = __uint_as_float(0x7F800000u);  // +inf

    unsigned mpack = 0xFFFFFFC0u;
    // keep mask in a register so (x & m) | t fuses to v_and_or_b32 (t stays SGPR)
    asm("" : "+v"(mpack));

    const char* gb = Eblob + (size_t)chunk * CHUNKB;

    stage_grp(gb, 0, buf0, lane);        // prologue: group 0 in flight

    for (int g = 0; g < NGRP2; ++g) {    // 32 groups x 2 tiles
        if (g < NGRP2 - 1) {
            stage_grp(gb, g + 1, buf0 + ((g + 1) & 1) * WBUF, lane);
            asm volatile("s_waitcnt vmcnt(5)" ::: "memory");  // g resident; g+1 in flight
        } else {
            asm volatile("s_waitcnt vmcnt(0)" ::: "memory");
        }
        __builtin_amdgcn_sched_barrier(0);  // rule #18: pin LDS reads after the wait
        const char* bb = buf0 + (g & 1) * WBUF;
#pragma unroll
        for (int tt = 0; tt < 2; ++tt) {
            half8 bh = *(const half8*)(bb + tt * 1024 + lane * 16);
            half8 bl = *(const half8*)(bb + 2048 + tt * 1024 + lane * 16);
            f32x4 eq = *(const f32x4*)(bb + 4096 + tt * 256 + (lane & 15) * 16);
            unsigned t = (unsigned)(g * 2 + tt);
#pragma unroll
            for (int qq = 0; qq < 4; ++qq) {
                f32x4 acc = __builtin_amdgcn_mfma_f32_16x16x32_f16(a_hi[qq], bh, eq, 0, 0, 0);
                acc = __builtin_amdgcn_mfma_f32_16x16x32_f16(a_hi[qq], bl, acc, 0, 0, 0);
                acc = __builtin_amdgcn_mfma_f32_16x16x32_f16(a_lo[qq], bh, acc, 0, 0, 0);
#pragma unroll
                for (int r = 0; r < 4; ++r) {
                    unsigned p = (__float_as_uint(acc[r]) & mpack) | t;   // v_and_or_b32
                    best[qq][r] = fminf(best[qq][r], __uint_as_float(p)); // v_min_f32
                }
            }
        }
    }

    // 16-lane column reduce per query row, then one atomicMin per query
#pragma unroll
    for (int qq = 0; qq < 4; ++qq)
#pragma unroll
        for (int r = 0; r < 4; ++r) {
            float d = best[qq][r];
            int t = (int)(__float_as_uint(d) & 63u);
            int code = chunk * CODES_PER_CH + (t << 4) + (lane & 15);
#pragma unroll
            for (int m = 1; m < 16; m <<= 1) {
                float od = __shfl_xor(d, m, 64);
                int oc = __shfl_xor(code, m, 64);
                if (od < d || (od == d && oc < code)) { d = od; code = oc; }
            }
            if ((lane & 15) == 0) {
                int row = ((lane >> 4) * 4) + r;
                int n = (wid * 4 + qq) * 16 + row;
                unsigned bits = __float_as_uint(d);
                unsigned s = ((int)bits >= 0) ? (bits | 0x80000000u) : ~bits;
                unsigned long long key = ((unsigned long long)s << 32) | (unsigned)code;
                atomicMin(&keys[n], key);
            }
        }
}

// ---- conv3x3 residual + fhat + loss + bincount + FUSED final scalars ----
__global__ __launch_bounds__(256) void k_conv(const unsigned long long* __restrict__ keys,
                                              const float* __restrict__ emb,
                                              const float* __restrict__ wp,
                                              const float* __restrict__ bias,
                                              const float* __restrict__ f,
                                              int* __restrict__ counts,
                                              float* __restrict__ out,
                                              float* __restrict__ lpart,
                                              int* __restrict__ done) {
    __shared__ float sZ[128 * 33];
    __shared__ float sW[9216];      // full [tap][cin][cout] weight block
    __shared__ float red[256];
    __shared__ int sfin;
    int blk = blockIdx.x;
    int b = blk >> 4;
    int r0 = (blk & 15) * 2;
    int tid = threadIdx.x;

    {   // stage weights: 2304 float4
        float4* dW = reinterpret_cast<float4*>(sW);
        const float4* sWp = reinterpret_cast<const float4*>(wp);
        for (int i = tid; i < 2304; i += 256) dW[i] = sWp[i];
    }
    {   // stage 4 rows (r0-1..r0+2)
        int px = tid >> 1, half = tid & 1;
        int row = px >> 5, col = px & 31;
        int gy = r0 - 1 + row;
        float* d = &sZ[px * 33 + half * 16];
        if (gy >= 0 && gy < 32) {
            int id = (int)(keys[b * HW + gy * 32 + col] & 0xFFFFFFFFULL);
            const float4* s = reinterpret_cast<const float4*>(emb + id * C + half * 16);
#pragma unroll
            for (int k = 0; k < 4; ++k) {
                float4 v = s[k];
                d[4 * k] = v.x; d[4 * k + 1] = v.y; d[4 * k + 2] = v.z; d[4 * k + 3] = v.w;
            }
        } else {
#pragma unroll
            for (int k = 0; k < 16; ++k) d[k] = 0.f;
        }
    }
    __syncthreads();

    int tx = tid & 31, ty = (tid >> 5) & 1, cg = tid >> 6;
    int co0 = cg * 8;
    int gy = r0 + ty;
    if (cg == 0) {
        int id = (int)(keys[b * HW + gy * 32 + tx] & 0xFFFFFFFFULL);
        atomicAdd(&counts[id], 1);
    }
    float acc[8];
#pragma unroll
    for (int u = 0; u < 8; ++u) acc[u] = bias[co0 + u];
    for (int dy = -1; dy <= 1; ++dy) {
        for (int dx = -1; dx <= 1; ++dx) {
            int gx = tx + dx;
            if (gx < 0 || gx >= 32) continue;
            const float* zp = &sZ[((ty + 1 + dy) * 32 + gx) * 33];
            int tap = (dy + 1) * 3 + (dx + 1);
            const float* wtap = &sW[tap * C * C + co0];
#pragma unroll
            for (int cin = 0; cin < C; ++cin) {
                float z = zp[cin];
                const f32x4* w4 = reinterpret_cast<const f32x4*>(wtap + cin * C);
                f32x4 wa = w4[0], wb = w4[1];
#pragma unroll
                for (int u = 0; u < 4; ++u) acc[u] = fmaf(z, wa[u], acc[u]);
#pragma unroll
                for (int u = 0; u < 4; ++u) acc[4 + u] = fmaf(z, wb[u], acc[4 + u]);
            }
        }
    }
    float lsum = 0.f;
#pragma unroll
    for (int u = 0; u < 8; ++u) {
        int cc = co0 + u;
        float zqv = sZ[((ty + 1) * 32 + tx) * 33 + cc];
        float fh = 0.5f * (zqv + acc[u]);   // h*(1-r) + (conv+b)*r, r=0.5
        int off = (b * C + cc) * HW + gy * 32 + tx;
        out[off] = fh;
        float diff = fh - f[off];
        lsum += diff * diff;
    }
    red[tid] = lsum;
    __syncthreads();
    for (int s = 128; s > 0; s >>= 1) {
        if (tid < s) red[tid] += red[tid + s];
        __syncthreads();
    }
    if (tid == 0) lpart[blk] = red[0];

    // ---- last-block fused finalization ----
    if (tid == 0) {
        __threadfence();                       // publish lpart + count atomics
        int v = atomicAdd(done, 1);
        sfin = (v == 255) ? 1 : 0;
    }
    __syncthreads();
    if (sfin) {
        __threadfence();                       // acquire all blocks' writes
        int* redi = (int*)sZ;                  // reuse LDS
        int used = 0;
        for (int i = tid; i < VOCAB; i += 256) used += (counts[i] != 0) ? 1 : 0;
        red[tid] = lpart[tid];
        redi[tid] = used;
        __syncthreads();
        for (int s = 128; s > 0; s >>= 1) {
            if (tid < s) { red[tid] += red[tid + s]; redi[tid] += redi[tid + s]; }
            __syncthreads();
        }
        if (tid == 0) {
            out[N_Q * C]     = 1.25f * red[0] / (float)(N_Q * C);      // (1+BETA)*MSE
            out[N_Q * C + 1] = 100.f * (float)redi[0] / (float)VOCAB;  // counts>=1
        }
    }
}

extern "C" void kernel_launch(void* const* d_in, const int* in_sizes, int n_in,
                              void* d_out, int out_size, void* d_ws, size_t ws_size,
                              hipStream_t stream) {
    const float* f     = (const float*)d_in[0];
    const float* emb   = (const float*)d_in[1];
    const float* convw = (const float*)d_in[2];
    const float* convb = (const float*)d_in[3];
    float* out = (float*)d_out;
    float* ws  = (float*)d_ws;

    // float-unit offsets (total ~2.9 MB)
    float*  wp     = ws;                              // 9216
    float*  lpart  = ws + 9216;                       // 256
    int*    done   = (int*)(ws + 9472);               // 16 (padded)
    int*    counts = (int*)(ws + 9488);               // 16384
    unsigned long long* keys = (unsigned long long*)(ws + 25872);  // 16384 u64 (8B-aligned)
    char*   Eblob  = (char*)(ws + 58640);             // 16 chunks x 160KB = 2.62 MB (16B-aligned)

    k_prepE<<<67, 256, 0, stream>>>(emb, Eblob, convw, wp, keys, counts, done);
    dim3 g2(64, VCH);
    k_argmin<<<g2, 256, 0, stream>>>(f, Eblob, keys);
    k_conv<<<256, 256, 0, stream>>>(keys, emb, wp, convb, f, counts, out, lpart, done);
}